// Round 1
// baseline (277.041 us; speedup 1.0000x reference)
//
#include <hip/hip_runtime.h>
#include <hip/hip_bf16.h>
#include <stdint.h>

#define B_DIM 8
#define T_DIM 2048
#define H_DIM 512
#define NC 32       // chunks per batch
#define LCH 64      // chunk length (NC*LCH == T_DIM)
#define BM 128
#define BN 128
#define BK 32

typedef float floatx4 __attribute__((ext_vector_type(4)));
typedef __bf16 bf16x8 __attribute__((ext_vector_type(8)));

// ---------------- K1: global min/max of e -> stats[0]=mn, stats[1]=1/(mx-mn)
__global__ void minmax_kernel(const float* __restrict__ e, float* __restrict__ stats) {
    const int n = B_DIM * T_DIM;
    int tid = threadIdx.x;
    float mn = 1e30f, mx = -1e30f;
    for (int i = tid; i < n; i += 256) {
        float v = e[i];
        mn = fminf(mn, v);
        mx = fmaxf(mx, v);
    }
    for (int off = 32; off > 0; off >>= 1) {
        mn = fminf(mn, __shfl_down(mn, off, 64));
        mx = fmaxf(mx, __shfl_down(mx, off, 64));
    }
    __shared__ float smn[4], smx[4];
    int wid = tid >> 6;
    if ((tid & 63) == 0) { smn[wid] = mn; smx[wid] = mx; }
    __syncthreads();
    if (tid == 0) {
        mn = fminf(fminf(smn[0], smn[1]), fminf(smn[2], smn[3]));
        mx = fmaxf(fmaxf(smx[0], smx[1]), fmaxf(smx[2], smx[3]));
        stats[0] = mn;
        stats[1] = 1.0f / (mx - mn);
    }
}

// ---------------- K2: per-chunk local scan (zero-init state), store L (fp32),
// PP (prefix products of multipliers), Ld (denominator local scan), h_bf (bf16 cast of h)
__global__ __launch_bounds__(512) void chunk_scan_kernel(
        const float* __restrict__ e, const float* __restrict__ h,
        const float* __restrict__ stats,
        float* __restrict__ L, float* __restrict__ PP, float* __restrict__ Ld,
        __hip_bfloat16* __restrict__ h_bf) {
    const int b = blockIdx.x, c = blockIdx.y, hd = threadIdx.x;
    const int t0 = c * LCH;
    const float mn = stats[0], sc = stats[1];
    const float* eb = e + b * T_DIM;
    const float* hp = h + ((size_t)b * T_DIM + t0) * H_DIM + hd;
    float* Lp = L + ((size_t)b * T_DIM + t0) * H_DIM + hd;
    __hip_bfloat16* hbp = h_bf + ((size_t)b * T_DIM + t0) * H_DIM + hd;

    float lv = 0.0f, ldv = 0.0f, pp = 1.0f;
    #pragma unroll 4
    for (int i = 0; i < LCH; ++i) {
        int t = t0 + i;
        float a = (t == 0) ? 0.0f : (eb[t - 1] - mn) * sc;  // multiplier A_t = x[t-1]
        float hv = hp[(size_t)i * H_DIM];
        lv = fmaf(a, lv, hv);
        ldv = fmaf(a, ldv, 1.0f);
        pp *= a;
        Lp[(size_t)i * H_DIM] = lv;
        hbp[(size_t)i * H_DIM] = __float2bfloat16(hv);
        if (hd == 0) { PP[b * T_DIM + t] = pp; Ld[b * T_DIM + t] = ldv; }
    }
}

// ---------------- K3: cross-chunk carry. S[b][c][hd] = numerator state entering chunk c.
__global__ __launch_bounds__(512) void carry_kernel(
        const float* __restrict__ L, const float* __restrict__ PP, const float* __restrict__ Ld,
        float* __restrict__ S, float* __restrict__ SD) {
    const int b = blockIdx.x, hd = threadIdx.x;
    float lend[NC], ppend[NC], ldend[NC];
    #pragma unroll
    for (int c = 0; c < NC; ++c) {
        int tend = c * LCH + LCH - 1;
        lend[c]  = L[((size_t)b * T_DIM + tend) * H_DIM + hd];
        ppend[c] = PP[b * T_DIM + tend];
        ldend[c] = Ld[b * T_DIM + tend];
    }
    float s = 0.0f, sd = 0.0f;
    #pragma unroll
    for (int c = 0; c < NC; ++c) {
        S[((size_t)b * NC + c) * H_DIM + hd] = s;
        if (hd == 0) SD[b * NC + c] = sd;
        s  = fmaf(ppend[c], s, lend[c]);
        sd = fmaf(ppend[c], sd, ldend[c]);
    }
}

// ---------------- K4: finalize h_agg = (PP*S + L) / (PP*SD + Ld) -> bf16
__global__ __launch_bounds__(256) void finalize_kernel(
        const float* __restrict__ L, const float* __restrict__ PP, const float* __restrict__ Ld,
        const float* __restrict__ S, const float* __restrict__ SD,
        __hip_bfloat16* __restrict__ hagg_bf) {
    size_t idx = (size_t)blockIdx.x * 256 + threadIdx.x;   // over B*T*H
    int hd = (int)(idx & (H_DIM - 1));
    size_t bt = idx >> 9;            // H=512
    int t = (int)(bt & (T_DIM - 1));
    int b = (int)(bt >> 11);
    int c = t / LCH;
    float pp = PP[bt];
    float n = fmaf(pp, S[((size_t)b * NC + c) * H_DIM + hd], L[idx]);
    float d = fmaf(pp, SD[b * NC + c], Ld[bt]);
    hagg_bf[idx] = __float2bfloat16(n / d);
}

// ---------------- K5: batched NT-GEMM, C[b,t,s] = (1/sqrt(H)) * A[b,t,:] . B[b,s,:]
__device__ __forceinline__ void async16(const void* g, void* l) {
    __builtin_amdgcn_global_load_lds(
        (__attribute__((address_space(1))) void*)g,
        (__attribute__((address_space(3))) void*)l,
        16, 0, 0);
}

__global__ __launch_bounds__(256) void gemm_kernel(
        const __hip_bfloat16* __restrict__ Abf,   // h_bf   [B][T][H]
        const __hip_bfloat16* __restrict__ Bbf,   // hagg_bf[B][T][H]
        float* __restrict__ C) {                  // [B][T][T]
    __shared__ __align__(16) __hip_bfloat16 As[BM * BK];
    __shared__ __align__(16) __hip_bfloat16 Bs[BN * BK];
    const int b = blockIdx.z;
    const int tm = blockIdx.x * BM;
    const int sn = blockIdx.y * BN;
    const int tid = threadIdx.x;
    const int lane = tid & 63;
    const int wave = tid >> 6;
    const int wm = (wave >> 1) * 64;
    const int wn = (wave & 1) * 64;
    const int l16 = lane & 15;
    const int quad = lane >> 4;

    // staging: thread tid loads 16B for LDS row (tid>>2), kcol (tid&3)*8; two 64-row halves
    const __hip_bfloat16* Ag = Abf + ((size_t)b * T_DIM + tm + (tid >> 2)) * H_DIM + (tid & 3) * 8;
    const __hip_bfloat16* Bg = Bbf + ((size_t)b * T_DIM + sn + (tid >> 2)) * H_DIM + (tid & 3) * 8;
    char* AsB = (char*)As;
    char* BsB = (char*)Bs;

    floatx4 zero = {0.0f, 0.0f, 0.0f, 0.0f};
    floatx4 acc[4][4];
    #pragma unroll
    for (int i = 0; i < 4; ++i)
        #pragma unroll
        for (int j = 0; j < 4; ++j) acc[i][j] = zero;

    for (int kk = 0; kk < H_DIM; kk += BK) {
        __syncthreads();   // protect previous iteration's LDS reads
        async16(Ag + kk,                AsB + tid * 16);
        async16(Ag + kk + 64 * H_DIM,   AsB + 4096 + tid * 16);
        async16(Bg + kk,                BsB + tid * 16);
        async16(Bg + kk + 64 * H_DIM,   BsB + 4096 + tid * 16);
        asm volatile("s_waitcnt vmcnt(0)" ::: "memory");
        __syncthreads();

        bf16x8 af[4], bfv[4];
        #pragma unroll
        for (int i = 0; i < 4; ++i) {
            af[i]  = *reinterpret_cast<const bf16x8*>(AsB + ((wm + i * 16 + l16) * BK + quad * 8) * 2);
            bfv[i] = *reinterpret_cast<const bf16x8*>(BsB + ((wn + i * 16 + l16) * BK + quad * 8) * 2);
        }
        #pragma unroll
        for (int i = 0; i < 4; ++i)
            #pragma unroll
            for (int j = 0; j < 4; ++j)
                acc[i][j] = __builtin_amdgcn_mfma_f32_16x16x32_bf16(af[i], bfv[j], acc[i][j], 0, 0, 0);
    }

    const float scale = 0.04419417382415922f;  // 1/sqrt(512)
    float* Cp = C + (size_t)b * T_DIM * T_DIM;
    #pragma unroll
    for (int i = 0; i < 4; ++i) {
        int row0 = tm + wm + i * 16 + quad * 4;
        #pragma unroll
        for (int j = 0; j < 4; ++j) {
            int col = sn + wn + j * 16 + l16;
            #pragma unroll
            for (int r = 0; r < 4; ++r)
                Cp[(size_t)(row0 + r) * T_DIM + col] = acc[i][j][r] * scale;
        }
    }
}

extern "C" void kernel_launch(void* const* d_in, const int* in_sizes, int n_in,
                              void* d_out, int out_size, void* d_ws, size_t ws_size,
                              hipStream_t stream) {
    const float* e = (const float*)d_in[0];
    const float* h = (const float*)d_in[1];
    // d_in[2] (ilens) is unused by the reference output.
    float* out = (float*)d_out;

    char* ws = (char*)d_ws;
    float* stats            = (float*)ws;                                   // 256 B
    __hip_bfloat16* h_bf    = (__hip_bfloat16*)(ws + 256);                  // 16 MB
    __hip_bfloat16* hagg_bf = (__hip_bfloat16*)(ws + 256 + (16u << 20));    // 16 MB
    float* L                = (float*)(ws + 256 + (32u << 20));             // 32 MB
    float* PP               = (float*)(ws + 256 + (64u << 20));             // 64 KB
    float* Ld               = (float*)(ws + 256 + (64u << 20) + (1u << 16));// 64 KB
    float* S                = (float*)(ws + 256 + (64u << 20) + (2u << 16));// 512 KB
    float* SD               = (float*)(ws + 256 + (64u << 20) + (2u << 16) + (512u << 10)); // small

    minmax_kernel<<<1, 256, 0, stream>>>(e, stats);
    chunk_scan_kernel<<<dim3(B_DIM, NC), 512, 0, stream>>>(e, h, stats, L, PP, Ld, h_bf);
    carry_kernel<<<B_DIM, 512, 0, stream>>>(L, PP, Ld, S, SD);
    finalize_kernel<<<(B_DIM * T_DIM * H_DIM) / 256, 256, 0, stream>>>(L, PP, Ld, S, SD, hagg_bf);
    gemm_kernel<<<dim3(T_DIM / BM, T_DIM / BN, B_DIM), 256, 0, stream>>>(h_bf, hagg_bf, out);
}

// Round 2
// 243.664 us; speedup vs baseline: 1.1370x; 1.1370x over previous
//
#include <hip/hip_runtime.h>
#include <hip/hip_bf16.h>
#include <stdint.h>

#define B_DIM 8
#define T_DIM 2048
#define H_DIM 512
#define NC 32       // chunks per batch
#define LCH 64      // chunk length (NC*LCH == T_DIM)
#define BM 128
#define BN 128
#define BK 32

typedef float floatx4 __attribute__((ext_vector_type(4)));
typedef __bf16 bf16x8 __attribute__((ext_vector_type(8)));

// ---------------- K1: global min/max of e -> stats[0]=mn, stats[1]=1/(mx-mn)
// 1024 threads, float4 loads: 16384 floats = 4096 float4 = 4 per thread.
__global__ __launch_bounds__(1024) void minmax_kernel(const float* __restrict__ e,
                                                      float* __restrict__ stats) {
    const float4* e4 = (const float4*)e;
    int tid = threadIdx.x;
    float mn = 1e30f, mx = -1e30f;
    #pragma unroll
    for (int i = 0; i < 4; ++i) {
        float4 v = e4[tid + i * 1024];
        mn = fminf(mn, fminf(fminf(v.x, v.y), fminf(v.z, v.w)));
        mx = fmaxf(mx, fmaxf(fmaxf(v.x, v.y), fmaxf(v.z, v.w)));
    }
    for (int off = 32; off > 0; off >>= 1) {
        mn = fminf(mn, __shfl_down(mn, off, 64));
        mx = fmaxf(mx, __shfl_down(mx, off, 64));
    }
    __shared__ float smn[16], smx[16];
    int wid = tid >> 6;
    if ((tid & 63) == 0) { smn[wid] = mn; smx[wid] = mx; }
    __syncthreads();
    if (tid == 0) {
        mn = smn[0]; mx = smx[0];
        #pragma unroll
        for (int w = 1; w < 16; ++w) { mn = fminf(mn, smn[w]); mx = fmaxf(mx, smx[w]); }
        stats[0] = mn;
        stats[1] = 1.0f / (mx - mn);
    }
}

// ---------------- K2: per-chunk local scan, emit ONLY chunk-end summaries + h_bf.
// Lend[b][c][hd] = numerator local-scan end; PPend/LDend = multiplier product /
// denominator local-scan end (scalar per chunk).
__global__ __launch_bounds__(512) void chunk_sum_kernel(
        const float* __restrict__ e, const float* __restrict__ h,
        const float* __restrict__ stats,
        __hip_bfloat16* __restrict__ h_bf,
        float* __restrict__ Lend, float* __restrict__ PPend, float* __restrict__ LDend) {
    const int b = blockIdx.x, c = blockIdx.y, hd = threadIdx.x;
    const int t0 = c * LCH;
    const float mn = stats[0], sc = stats[1];
    const float* eb = e + b * T_DIM;
    const float* hp = h + ((size_t)b * T_DIM + t0) * H_DIM + hd;
    __hip_bfloat16* hbp = h_bf + ((size_t)b * T_DIM + t0) * H_DIM + hd;

    float lv = 0.0f, ldv = 0.0f, pp = 1.0f;
    #pragma unroll 8
    for (int i = 0; i < LCH; ++i) {
        int t = t0 + i;
        float a = (t == 0) ? 0.0f : (eb[t - 1] - mn) * sc;  // multiplier A_t = x[t-1]
        float hv = hp[(size_t)i * H_DIM];
        lv = fmaf(a, lv, hv);
        ldv = fmaf(a, ldv, 1.0f);
        pp *= a;
        hbp[(size_t)i * H_DIM] = __float2bfloat16(hv);
    }
    Lend[((size_t)b * NC + c) * H_DIM + hd] = lv;
    if (hd == 0) { PPend[b * NC + c] = pp; LDend[b * NC + c] = ldv; }
}

// ---------------- K3: cross-chunk carry. S[b][c][hd] = numerator state entering chunk c.
__global__ __launch_bounds__(512) void carry_kernel(
        const float* __restrict__ Lend, const float* __restrict__ PPend,
        const float* __restrict__ LDend,
        float* __restrict__ S, float* __restrict__ SD) {
    const int b = blockIdx.x, hd = threadIdx.x;
    float s = 0.0f, sd = 0.0f;
    #pragma unroll
    for (int c = 0; c < NC; ++c) {
        S[((size_t)b * NC + c) * H_DIM + hd] = s;
        if (hd == 0) SD[b * NC + c] = sd;
        float pe = PPend[b * NC + c];
        s  = fmaf(pe, s,  Lend[((size_t)b * NC + c) * H_DIM + hd]);
        sd = fmaf(pe, sd, LDend[b * NC + c]);
    }
}

// ---------------- K4: rescan chunk from h_bf with carried-in state, emit h_agg (bf16).
__global__ __launch_bounds__(512) void rescan_kernel(
        const float* __restrict__ e, const __hip_bfloat16* __restrict__ h_bf,
        const float* __restrict__ stats,
        const float* __restrict__ S, const float* __restrict__ SD,
        __hip_bfloat16* __restrict__ hagg_bf) {
    const int b = blockIdx.x, c = blockIdx.y, hd = threadIdx.x;
    const int t0 = c * LCH;
    const float mn = stats[0], sc = stats[1];
    const float* eb = e + b * T_DIM;
    const __hip_bfloat16* hbp = h_bf + ((size_t)b * T_DIM + t0) * H_DIM + hd;
    __hip_bfloat16* hop = hagg_bf + ((size_t)b * T_DIM + t0) * H_DIM + hd;

    float s  = S[((size_t)b * NC + c) * H_DIM + hd];
    float sd = SD[b * NC + c];
    #pragma unroll 8
    for (int i = 0; i < LCH; ++i) {
        int t = t0 + i;
        float a = (t == 0) ? 0.0f : (eb[t - 1] - mn) * sc;
        float hv = __bfloat162float(hbp[(size_t)i * H_DIM]);
        s  = fmaf(a, s, hv);
        sd = fmaf(a, sd, 1.0f);
        hop[(size_t)i * H_DIM] = __float2bfloat16(s / sd);
    }
}

// ---------------- K5: batched NT-GEMM, C[b,t,s] = (1/sqrt(H)) * A[b,t,:] . B[b,s,:]
__device__ __forceinline__ void async16(const void* g, void* l) {
    __builtin_amdgcn_global_load_lds(
        (__attribute__((address_space(1))) void*)g,
        (__attribute__((address_space(3))) void*)l,
        16, 0, 0);
}

__global__ __launch_bounds__(256) void gemm_kernel(
        const __hip_bfloat16* __restrict__ Abf,   // h_bf   [B][T][H]
        const __hip_bfloat16* __restrict__ Bbf,   // hagg_bf[B][T][H]
        float* __restrict__ C) {                  // [B][T][T]
    __shared__ __align__(16) __hip_bfloat16 As[BM * BK];
    __shared__ __align__(16) __hip_bfloat16 Bs[BN * BK];
    const int b = blockIdx.z;
    const int tm = blockIdx.x * BM;
    const int sn = blockIdx.y * BN;
    const int tid = threadIdx.x;
    const int lane = tid & 63;
    const int wave = tid >> 6;
    const int wm = (wave >> 1) * 64;
    const int wn = (wave & 1) * 64;
    const int l16 = lane & 15;
    const int quad = lane >> 4;

    const __hip_bfloat16* Ag = Abf + ((size_t)b * T_DIM + tm + (tid >> 2)) * H_DIM + (tid & 3) * 8;
    const __hip_bfloat16* Bg = Bbf + ((size_t)b * T_DIM + sn + (tid >> 2)) * H_DIM + (tid & 3) * 8;
    char* AsB = (char*)As;
    char* BsB = (char*)Bs;

    floatx4 zero = {0.0f, 0.0f, 0.0f, 0.0f};
    floatx4 acc[4][4];
    #pragma unroll
    for (int i = 0; i < 4; ++i)
        #pragma unroll
        for (int j = 0; j < 4; ++j) acc[i][j] = zero;

    for (int kk = 0; kk < H_DIM; kk += BK) {
        __syncthreads();   // protect previous iteration's LDS reads
        async16(Ag + kk,                AsB + tid * 16);
        async16(Ag + kk + 64 * H_DIM,   AsB + 4096 + tid * 16);
        async16(Bg + kk,                BsB + tid * 16);
        async16(Bg + kk + 64 * H_DIM,   BsB + 4096 + tid * 16);
        asm volatile("s_waitcnt vmcnt(0)" ::: "memory");
        __syncthreads();

        bf16x8 af[4], bfv[4];
        #pragma unroll
        for (int i = 0; i < 4; ++i) {
            af[i]  = *reinterpret_cast<const bf16x8*>(AsB + ((wm + i * 16 + l16) * BK + quad * 8) * 2);
            bfv[i] = *reinterpret_cast<const bf16x8*>(BsB + ((wn + i * 16 + l16) * BK + quad * 8) * 2);
        }
        #pragma unroll
        for (int i = 0; i < 4; ++i)
            #pragma unroll
            for (int j = 0; j < 4; ++j)
                acc[i][j] = __builtin_amdgcn_mfma_f32_16x16x32_bf16(af[i], bfv[j], acc[i][j], 0, 0, 0);
    }

    const float scale = 0.04419417382415922f;  // 1/sqrt(512)
    float* Cp = C + (size_t)b * T_DIM * T_DIM;
    #pragma unroll
    for (int i = 0; i < 4; ++i) {
        int row0 = tm + wm + i * 16 + quad * 4;
        #pragma unroll
        for (int j = 0; j < 4; ++j) {
            int col = sn + wn + j * 16 + l16;
            #pragma unroll
            for (int r = 0; r < 4; ++r)
                Cp[(size_t)(row0 + r) * T_DIM + col] = acc[i][j][r] * scale;
        }
    }
}

extern "C" void kernel_launch(void* const* d_in, const int* in_sizes, int n_in,
                              void* d_out, int out_size, void* d_ws, size_t ws_size,
                              hipStream_t stream) {
    const float* e = (const float*)d_in[0];
    const float* h = (const float*)d_in[1];
    // d_in[2] (ilens) is unused by the reference output.
    float* out = (float*)d_out;

    char* ws = (char*)d_ws;
    float* stats            = (float*)ws;                                    // 256 B
    __hip_bfloat16* h_bf    = (__hip_bfloat16*)(ws + 256);                   // 16 MB
    __hip_bfloat16* hagg_bf = (__hip_bfloat16*)(ws + 256 + (16u << 20));     // 16 MB
    char* p = ws + 256 + (32u << 20);
    float* Lend  = (float*)p;                    p += (size_t)B_DIM * NC * H_DIM * 4;  // 512 KB
    float* PPend = (float*)p;                    p += B_DIM * NC * 4;                  // 1 KB
    float* LDend = (float*)p;                    p += B_DIM * NC * 4;                  // 1 KB
    float* S     = (float*)p;                    p += (size_t)B_DIM * NC * H_DIM * 4;  // 512 KB
    float* SD    = (float*)p;

    minmax_kernel<<<1, 1024, 0, stream>>>(e, stats);
    chunk_sum_kernel<<<dim3(B_DIM, NC), 512, 0, stream>>>(e, h, stats, h_bf, Lend, PPend, LDend);
    carry_kernel<<<B_DIM, 512, 0, stream>>>(Lend, PPend, LDend, S, SD);
    rescan_kernel<<<dim3(B_DIM, NC), 512, 0, stream>>>(e, h_bf, stats, S, SD, hagg_bf);
    gemm_kernel<<<dim3(T_DIM / BM, T_DIM / BN, B_DIM), 256, 0, stream>>>(h_bf, hagg_bf, out);
}